// Round 4
// baseline (116.311 us; speedup 1.0000x reference)
//
#include <hip/hip_runtime.h>
#include <hip/hip_bf16.h>

#define BB 4
#define NN 256
#define KK 32
#define DD 32
#define HH 8
#define NROWS 1024            // proj rows: e = 1..1024 stored at e-1
#define NPTS (BB * NN * NN)   // 262144
#define NNSQ (NN * NN)        // 65536
#define TPB 1024              // threads (= points) per block
#define NBLK (NPTS / TPB)     // 256 blocks = 1 per CU

typedef __attribute__((ext_vector_type(8))) unsigned short ushort8;
typedef __attribute__((ext_vector_type(4))) int iv4;
typedef __attribute__((ext_vector_type(2))) int iv2;

__device__ __forceinline__ unsigned short f2bf(float f) {
    unsigned u = __float_as_uint(f);
    unsigned r = (u + 0x7FFFu + ((u >> 16) & 1u)) >> 16;
    return (unsigned short)r;
}

__device__ __forceinline__ void gload16(const void* g, void* l) {
    __builtin_amdgcn_global_load_lds(
        (const __attribute__((address_space(1))) void*)g,
        (__attribute__((address_space(3))) void*)l,
        16, 0, 0);
}

// ---------------------------------------------------------------------------
// Kernel A: proj[k][e-1][h] = sum_d feat[e][d] * W[k][d][h]   (bf16, e=1..1024)
// ---------------------------------------------------------------------------
__global__ __launch_bounds__(256) void build_proj_bf16(
    const float* __restrict__ feat,    // [1025][32]
    const float* __restrict__ w,       // [32][256] (d*8+h)
    unsigned short* __restrict__ proj) // [32][1024][8]
{
    int t  = blockIdx.x * 256 + threadIdx.x;  // 0..32767
    int k  = t >> 10;                         // uniform per block
    int e  = (t & 1023) + 1;

    const float* frow = feat + (size_t)e * DD;
    const float* wrow = w + (size_t)k * DD * HH;

    float acc[HH];
#pragma unroll
    for (int h = 0; h < HH; ++h) acc[h] = 0.0f;

#pragma unroll
    for (int d = 0; d < DD; ++d) {
        float f = frow[d];
#pragma unroll
        for (int h = 0; h < HH; ++h) acc[h] = fmaf(f, wrow[d * HH + h], acc[h]);
    }

    ushort8 o;
#pragma unroll
    for (int h = 0; h < HH; ++h) o[h] = f2bf(acc[h]);
    *(ushort8*)(proj + (size_t)t * HH) = o;
}

// ---------------------------------------------------------------------------
// Kernel B: 1024 points per block, 256 blocks (1/CU).
//  - indices transposed once into LDS via coalesced nt-int4 loads
//  - k-loop gathers 16B bf16 rows from a double-buffered 16KB LDS slice
//    staged with global_load_lds; one __syncthreads per k (stage issued
//    after the barrier -> latency hides under next compute phase)
// E = ints per index element (2 = int64 input, 1 = int32).
// ---------------------------------------------------------------------------
template <int E>
__global__ __launch_bounds__(TPB) void attn_bias_lds2(
    const int* __restrict__ sp,               // [NPTS] (*E)
    const int* __restrict__ ei,               // [NPTS*KK] (*E)
    const float* __restrict__ semb,           // [512][8]
    const unsigned short* __restrict__ proj,  // [32][1024][8] bf16
    float* __restrict__ out)                  // [BB][HH][NNSQ]
{
    __shared__ __align__(16) unsigned short tbuf[2][NROWS * HH]; // 2 x 16KB
    __shared__ unsigned short ibuf[KK][TPB];                     // 64KB

    const int tid = threadIdx.x;
    const int p0  = blockIdx.x * TPB;

    auto stage = [&](int k, int slot) {
        gload16(proj + (size_t)k * (NROWS * HH) + (size_t)tid * HH,
                &tbuf[slot][tid * HH]);
    };

    // stage slices 0 and 1 (drained by the prologue __syncthreads)
    stage(0, 0);
    stage(1, 1);

    // ---- transpose indices into ibuf (coalesced, non-temporal) ----
    const iv4* EI4 = (const iv4*)ei;
    const size_t base4 = (size_t)p0 * (8 * E);   // int4s per point = 8E
    if (E == 2) {
#pragma unroll
        for (int c = 0; c < 16; ++c) {
            int j  = c * TPB + tid;
            int pt = j >> 4;
            int q  = j & 15;
            iv4 v = __builtin_nontemporal_load(&EI4[base4 + (size_t)pt * 16 + q]);
            int k0 = q * 2;
            ibuf[k0    ][pt ^ ((k0    ) << 2)] = (unsigned short)v.x;
            ibuf[k0 + 1][pt ^ ((k0 + 1) << 2)] = (unsigned short)v.z;
        }
    } else {
#pragma unroll
        for (int c = 0; c < 8; ++c) {
            int j  = c * TPB + tid;
            int pt = j >> 3;
            int q  = j & 7;
            iv4 v = __builtin_nontemporal_load(&EI4[base4 + (size_t)pt * 8 + q]);
            int k0 = q * 4;
            ibuf[k0    ][pt ^ ((k0    ) << 2)] = (unsigned short)v.x;
            ibuf[k0 + 1][pt ^ ((k0 + 1) << 2)] = (unsigned short)v.y;
            ibuf[k0 + 2][pt ^ ((k0 + 2) << 2)] = (unsigned short)v.z;
            ibuf[k0 + 3][pt ^ ((k0 + 3) << 2)] = (unsigned short)v.w;
        }
    }

    __syncthreads();   // drains stage(0/1) + index transpose

    float acc[HH];
#pragma unroll
    for (int h = 0; h < HH; ++h) acc[h] = 0.0f;
    int cnt = 0;

    // ---- main k loop: compute(k) | sync | issue stage(k+2) ----
#pragma unroll
    for (int k = 0; k < KK; ++k) {
        int   e = ibuf[k][tid ^ (k << 2)];
        int   r = e ? (e - 1) : 0;             // e==0 -> row 0, masked by m
        float m = e ? 1.0f : 0.0f;
        cnt += (e != 0);
        ushort8 row = *(const ushort8*)&tbuf[k & 1][r * HH];
#pragma unroll
        for (int h = 0; h < HH; ++h)
            acc[h] = fmaf(m, __uint_as_float(((unsigned)row[h]) << 16), acc[h]);

        __syncthreads();                       // reads of buf[k&1] done; stage(k+1) drained
        if (k + 2 < KK) stage(k + 2, k & 1);   // issued AFTER barrier: hides under compute(k+1)
    }

    // ---- epilogue: spatial bias + write ----
    const int p = p0 + tid;
    int s;
    if (E == 2) {
        iv2 sv = __builtin_nontemporal_load(&((const iv2*)sp)[p]);
        s = sv.x;
    } else {
        s = sp[p];
    }
    const float4* srow = (const float4*)(semb + (size_t)s * HH);
    float4 s0 = srow[0], s1 = srow[1];
    float sb[HH] = {s0.x, s0.y, s0.z, s0.w, s1.x, s1.y, s1.z, s1.w};

    float inv = 1.0f / (float)(cnt ? cnt : 1);
    float* o = out + (size_t)(p >> 16) * (HH * NNSQ) + (p & (NNSQ - 1));
#pragma unroll
    for (int h = 0; h < HH; ++h)
        __builtin_nontemporal_store(sb[h] + acc[h] * inv, &o[(size_t)h * NNSQ]);
}

extern "C" void kernel_launch(void* const* d_in, const int* in_sizes, int n_in,
                              void* d_out, int out_size, void* d_ws, size_t ws_size,
                              hipStream_t stream) {
    const int*   sp = (const int*)d_in[0];    // spatial_pos  [4,256,256]
    const int*   ei = (const int*)d_in[1];    // edge_input   [4,256,256,32]
    const float* se = (const float*)d_in[2];  // spatial_emb  [512,8]
    const float* fe = (const float*)d_in[3];  // edge_feat_emb[1025,32]
    const float* pw = (const float*)d_in[4];  // edge_pos_emb [32,256]
    float* out = (float*)d_out;

    const bool i64 = (in_sizes[0] == 2 * NPTS);
    unsigned short* proj = (unsigned short*)d_ws;   // 32*1024*8*2 = 512KB

    build_proj_bf16<<<128, 256, 0, stream>>>(fe, pw, proj);

    if (i64) attn_bias_lds2<2><<<NBLK, TPB, 0, stream>>>(sp, ei, se, proj, out);
    else     attn_bias_lds2<1><<<NBLK, TPB, 0, stream>>>(sp, ei, se, proj, out);
}

// Round 5
// 27.036 us; speedup vs baseline: 4.3021x; 4.3021x over previous
//
#include <hip/hip_runtime.h>
#include <hip/hip_bf16.h>

#define BB 4
#define NN 256
#define KK 32
#define DD 32
#define HH 8
#define NROWS 1024            // proj rows: e = 1..1024 stored at e-1
#define NPTS (BB * NN * NN)   // 262144
#define NNSQ (NN * NN)        // 65536
#define TPB 1024              // threads (= points) per block
#define NBLK (NPTS / TPB)     // 256 blocks = 1 per CU
#define NPH 16                // phases in k-loop
#define PK 2                  // k-slices per phase
#define SLICE_US (NROWS * HH) // 8192 ushorts = 16KB per slice

typedef __attribute__((ext_vector_type(8))) unsigned short ushort8;
typedef __attribute__((ext_vector_type(4))) int iv4;

__device__ __forceinline__ unsigned short f2bf(float f) {
    unsigned u = __float_as_uint(f);
    unsigned r = (u + 0x7FFFu + ((u >> 16) & 1u)) >> 16;
    return (unsigned short)r;
}

// ---------------------------------------------------------------------------
// Kernel A: proj[k][e-1][h] = sum_d feat[e][d] * W[k][d][h]   (bf16, e=1..1024)
// ---------------------------------------------------------------------------
__global__ __launch_bounds__(256) void build_proj_bf16(
    const float* __restrict__ feat,    // [1025][32]
    const float* __restrict__ w,       // [32][256] (d*8+h)
    unsigned short* __restrict__ proj) // [32][1024][8]
{
    int t  = blockIdx.x * 256 + threadIdx.x;  // 0..32767
    int k  = t >> 10;                         // uniform per block
    int e  = (t & 1023) + 1;

    const float* frow = feat + (size_t)e * DD;
    const float* wrow = w + (size_t)k * DD * HH;

    float acc[HH];
#pragma unroll
    for (int h = 0; h < HH; ++h) acc[h] = 0.0f;

#pragma unroll
    for (int d = 0; d < DD; ++d) {
        float f = frow[d];
#pragma unroll
        for (int h = 0; h < HH; ++h) acc[h] = fmaf(f, wrow[d * HH + h], acc[h]);
    }

    ushort8 o;
#pragma unroll
    for (int h = 0; h < HH; ++h) o[h] = f2bf(acc[h]);
    *(ushort8*)(proj + (size_t)t * HH) = o;
}

// ---------------------------------------------------------------------------
// Kernel B: 1024 points/block, 256 blocks (1/CU).
// - indices transposed once into padded ibuf (write banks <=2-way: stride 1026)
// - 16 phases x 2 slices; next phase prefetched to 8 named VGPRs (plain
//   global float4 loads), written to the other LDS buffer between barriers.
// - no global_load_lds, no inline asm, no nt, #pragma unroll 1 main loop.
// E = ints per index element (2 = int64 input, 1 = int32).
// ---------------------------------------------------------------------------
template <int E>
__global__ __launch_bounds__(TPB) void attn_bias_v5(
    const int* __restrict__ sp,               // [NPTS] (*E)
    const int* __restrict__ ei,               // [NPTS*KK] (*E)
    const float* __restrict__ semb,           // [512][8]
    const unsigned short* __restrict__ proj,  // [32][1024][8] bf16
    float* __restrict__ out)                  // [BB][HH][NNSQ]
{
    __shared__ __align__(16) unsigned short tbuf[2][PK * SLICE_US]; // 2 x 32KB
    __shared__ unsigned short ibuf[KK][TPB + 2];                    // stride 1026: write-conflict-free

    const int tid = threadIdx.x;
    const int p0  = blockIdx.x * TPB;

    const float4* P4 = (const float4*)proj;   // 16B units; phase q = [q*2048, q*2048+2048)

    // ---- prefetch phase 0 into regs ----
    float4 ra = P4[tid];
    float4 rb = P4[1024 + tid];

    // ---- transpose indices into ibuf (coalesced int4 loads, tiny live state) ----
    const iv4* EI4 = (const iv4*)ei;
    const size_t base4 = (size_t)p0 * (8 * E);   // int4s per point = 8E
    if (E == 2) {
#pragma unroll 4
        for (int c = 0; c < 16; ++c) {
            int j  = c * TPB + tid;
            int pt = j >> 4;
            int q  = j & 15;
            iv4 v  = EI4[base4 + (size_t)pt * 16 + q];
            ibuf[2 * q    ][pt] = (unsigned short)v.x;   // hop 2q  (int64 low word)
            ibuf[2 * q + 1][pt] = (unsigned short)v.z;   // hop 2q+1
        }
    } else {
#pragma unroll 4
        for (int c = 0; c < 8; ++c) {
            int j  = c * TPB + tid;
            int pt = j >> 3;
            int q  = j & 7;
            iv4 v  = EI4[base4 + (size_t)pt * 8 + q];
            ibuf[4 * q    ][pt] = (unsigned short)v.x;
            ibuf[4 * q + 1][pt] = (unsigned short)v.y;
            ibuf[4 * q + 2][pt] = (unsigned short)v.z;
            ibuf[4 * q + 3][pt] = (unsigned short)v.w;
        }
    }

    // ---- write phase 0 to LDS buf0, prefetch phase 1 ----
    *(float4*)&tbuf[0][tid * 8]        = ra;   // lane*16B: conflict-free
    *(float4*)&tbuf[0][SLICE_US + tid * 8] = rb;
    ra = P4[2048 + tid];
    rb = P4[2048 + 1024 + tid];

    __syncthreads();   // ibuf + buf0 visible

    float acc[HH];
#pragma unroll
    for (int h = 0; h < HH; ++h) acc[h] = 0.0f;
    int cnt = 0;

    // ---- main phase loop ----
#pragma unroll 1
    for (int p = 0; p < NPH; ++p) {
        const unsigned short* tb = tbuf[p & 1];

        int e0 = ibuf[2 * p    ][tid];
        int e1 = ibuf[2 * p + 1][tid];
        int r0 = e0 ? (e0 - 1) : 0;
        int r1 = e1 ? (e1 - 1) : 0;
        float m0 = e0 ? 1.0f : 0.0f;
        float m1 = e1 ? 1.0f : 0.0f;
        cnt += (e0 != 0) + (e1 != 0);

        ushort8 w0 = *(const ushort8*)&tb[r0 * 8];
        ushort8 w1 = *(const ushort8*)&tb[SLICE_US + r1 * 8];
#pragma unroll
        for (int h = 0; h < HH; ++h) {
            acc[h] = fmaf(m0, __uint_as_float(((unsigned)w0[h]) << 16), acc[h]);
            acc[h] = fmaf(m1, __uint_as_float(((unsigned)w1[h]) << 16), acc[h]);
        }

        if (p < NPH - 1) {
            __syncthreads();   // everyone done reading tbuf[(p+1)&1]
            unsigned short* wb = tbuf[(p + 1) & 1];
            *(float4*)&wb[tid * 8]        = ra;   // compiler waits vmcnt on ra/rb here
            *(float4*)&wb[SLICE_US + tid * 8] = rb;
            if (p < NPH - 2) {
                ra = P4[(size_t)(p + 2) * 2048 + tid];
                rb = P4[(size_t)(p + 2) * 2048 + 1024 + tid];
            }
            __syncthreads();   // new phase visible
        }
    }

    // ---- epilogue: spatial bias + write ----
    const int p = p0 + tid;
    int s;
    if (E == 2) s = (int)((const long long*)sp)[p];
    else        s = sp[p];
    const float4* srow = (const float4*)(semb + (size_t)s * HH);
    float4 s0 = srow[0], s1 = srow[1];
    float sb[HH] = {s0.x, s0.y, s0.z, s0.w, s1.x, s1.y, s1.z, s1.w};

    float inv = 1.0f / (float)(cnt ? cnt : 1);
    float* o = out + (size_t)(p >> 16) * (HH * NNSQ) + (p & (NNSQ - 1));
#pragma unroll
    for (int h = 0; h < HH; ++h)
        o[(size_t)h * NNSQ] = sb[h] + acc[h] * inv;
}

extern "C" void kernel_launch(void* const* d_in, const int* in_sizes, int n_in,
                              void* d_out, int out_size, void* d_ws, size_t ws_size,
                              hipStream_t stream) {
    const int*   sp = (const int*)d_in[0];    // spatial_pos  [4,256,256]
    const int*   ei = (const int*)d_in[1];    // edge_input   [4,256,256,32]
    const float* se = (const float*)d_in[2];  // spatial_emb  [512,8]
    const float* fe = (const float*)d_in[3];  // edge_feat_emb[1025,32]
    const float* pw = (const float*)d_in[4];  // edge_pos_emb [32,256]
    float* out = (float*)d_out;

    const bool i64 = (in_sizes[0] == 2 * NPTS);
    unsigned short* proj = (unsigned short*)d_ws;   // 32*1024*8*2 = 512KB

    build_proj_bf16<<<128, 256, 0, stream>>>(fe, pw, proj);

    if (i64) attn_bias_v5<2><<<NBLK, TPB, 0, stream>>>(sp, ei, se, proj, out);
    else     attn_bias_v5<1><<<NBLK, TPB, 0, stream>>>(sp, ei, se, proj, out);
}